// Round 1
// baseline (1968.525 us; speedup 1.0000x reference)
//
#include <hip/hip_runtime.h>
#include <hip/hip_bf16.h>
#include <math.h>

#define BATCH   16384
#define CIN     128
#define COUT    128
#define NK      45      // real coefficients
#define KP      48      // padded k slots
#define BB      8       // batches per block
#define NTHR    384     // 48 x 8 thread grid (6 waves)
#define IT      16      // i-chunk size
#define NCHUNK  (CIN / IT)   // 8

// Pre-kernel: WT[g][i][o] = W[o][i][g] * (2*pi*sqrt(4*pi/(4g+1)))/CIN
// W layout: weights[o][i][g], flat = o*640 + i*5 + g   (128*128*5 elements)
// WT layout: flat = g*16384 + i*128 + o
__global__ void wtrans_kernel(const float* __restrict__ W, float* __restrict__ WT) {
    int e = blockIdx.x * 256 + threadIdx.x;
    if (e >= 5 * CIN * COUT) return;
    int g   = e >> 14;         // / 16384
    int rem = e & 16383;
    int i   = rem >> 7;        // / 128
    int o   = rem & 127;
    float scale = 6.283185307179586f *
                  sqrtf(12.566370614359172f / (4.0f * (float)g + 1.0f)) / 128.0f;
    WT[e] = W[o * 640 + i * 5 + g] * scale;
}

__global__ __launch_bounds__(NTHR)
void sphconv_kernel(const float* __restrict__ x,
                    const float* __restrict__ WT,
                    float* __restrict__ out) {
    // x_t[i][k*8 + b] : 16 x 384 floats = 24 KB
    // w_t[g][i][o]    : 5 x 16 x 128 floats = 40 KB
    __shared__ float x_t[IT][KP * BB];
    __shared__ float w_t[5][IT][COUT];

    const int t  = threadIdx.x;
    const int rt = t % KP;           // k slot (0..47)
    const int ct = t / KP;           // o-block (0..7), covers o = ct*16 .. +15
    const int b0 = blockIdx.x * BB;
    const int k  = rt;
    // group of k: boundaries 1, 6, 15, 28
    const int g = (k >= 28) ? 4 : (k >= 15) ? 3 : (k >= 6) ? 2 : (k >= 1) ? 1 : 0;

    float acc[BB][16];
#pragma unroll
    for (int b = 0; b < BB; ++b)
#pragma unroll
        for (int o = 0; o < 16; ++o) acc[b][o] = 0.0f;

#pragma unroll 1
    for (int it = 0; it < NCHUNK; ++it) {
        // ---- stage x: 8b * 16i * 45k = 5760 = 384 * 15 elements ----
        // e = (i*45 + kk)*8 + b  (b innermost -> sequential LDS writes)
#pragma unroll
        for (int j = 0; j < 15; ++j) {
            int e  = t + NTHR * j;
            int b  = e & 7;
            int ik = e >> 3;           // < 720
            int i  = ik / 45;
            int kk = ik - i * 45;
            x_t[i][kk * 8 + b] =
                x[(size_t)(b0 + b) * (CIN * NK) + (size_t)(it * IT + i) * NK + kk];
        }
        // ---- stage W: 5g * 16i * 128o = 10240 elements ----
        for (int e = t; e < 5 * IT * COUT; e += NTHR) {
            int gg  = e >> 11;          // / (16*128)
            int rem = e & 2047;         // i*128 + o
            ((float*)w_t)[e] = WT[gg * (CIN * COUT) + it * (IT * COUT) + rem];
        }
        __syncthreads();

        // ---- compute: per thread 8b x 16o outer product per i ----
#pragma unroll
        for (int i = 0; i < IT; ++i) {
            float xv[BB];
            float4 xa = *(const float4*)&x_t[i][rt * 8 + 0];
            float4 xb = *(const float4*)&x_t[i][rt * 8 + 4];
            xv[0] = xa.x; xv[1] = xa.y; xv[2] = xa.z; xv[3] = xa.w;
            xv[4] = xb.x; xv[5] = xb.y; xv[6] = xb.z; xv[7] = xb.w;
            float wv[16];
#pragma unroll
            for (int q = 0; q < 4; ++q) {
                float4 w4 = *(const float4*)&w_t[g][i][ct * 16 + q * 4];
                wv[q * 4 + 0] = w4.x; wv[q * 4 + 1] = w4.y;
                wv[q * 4 + 2] = w4.z; wv[q * 4 + 3] = w4.w;
            }
#pragma unroll
            for (int b = 0; b < BB; ++b)
#pragma unroll
                for (int o = 0; o < 16; ++o)
                    acc[b][o] = fmaf(xv[b], wv[o], acc[b][o]);
        }
        __syncthreads();
    }

    // ---- epilogue: scale already folded into WT ----
    if (k < NK) {
#pragma unroll
        for (int b = 0; b < BB; ++b) {
            size_t base = (size_t)(b0 + b) * (COUT * NK) + (size_t)k;
#pragma unroll
            for (int o = 0; o < 16; ++o) {
                out[base + (size_t)(ct * 16 + o) * NK] = acc[b][o];
            }
        }
    }
}

extern "C" void kernel_launch(void* const* d_in, const int* in_sizes, int n_in,
                              void* d_out, int out_size, void* d_ws, size_t ws_size,
                              hipStream_t stream) {
    const float* x = (const float*)d_in[0];   // (16384, 128, 45) f32
    const float* w = (const float*)d_in[1];   // (128, 128, 5)   f32
    float* out = (float*)d_out;               // (16384, 128, 45) f32
    float* wt  = (float*)d_ws;                // 5*128*128 floats = 320 KB scratch

    wtrans_kernel<<<(5 * CIN * COUT + 255) / 256, 256, 0, stream>>>(w, wt);
    sphconv_kernel<<<BATCH / BB, NTHR, 0, stream>>>(x, wt, out);
}

// Round 4
// 739.558 us; speedup vs baseline: 2.6618x; 2.6618x over previous
//
#include <hip/hip_runtime.h>
#include <hip/hip_bf16.h>
#include <math.h>

typedef float f32x4 __attribute__((ext_vector_type(4)));
typedef short bf16x8 __attribute__((ext_vector_type(8)));

#define NK     45
#define NSLOT  50      // k padded per group to even slot counts: 2,6,10,14,18
#define BB     8       // batches per block
#define NTHR   1024    // 16 waves

// ---- prep: wt[g][o][i] = bf16( W[o][i][g] * 2*pi*sqrt(4*pi/(4g+1)) / 128 ) ----
__global__ void wprep_kernel(const float* __restrict__ W, unsigned short* __restrict__ wt) {
    int e = blockIdx.x * 256 + threadIdx.x;
    if (e >= 5 * 128 * 128) return;
    int g = e >> 14;
    int o = (e >> 7) & 127;
    int i = e & 127;
    float s = 6.283185307179586f * sqrtf(12.566370614359172f / (4.0f * (float)g + 1.0f))
              * (1.0f / 128.0f);
    float v = W[o * 640 + i * 5 + g] * s;
    __hip_bfloat16 h = __float2bfloat16(v);
    unsigned short u;
    __builtin_memcpy(&u, &h, 2);
    wt[e] = u;
}

// slot(k) = k + g(k); pad slots (never written/stored): 1, 7, 17, 31, 49
__device__ __forceinline__ int kgrp(int k) {
    return (k >= 28) ? 4 : (k >= 15) ? 3 : (k >= 6) ? 2 : (k >= 1) ? 1 : 0;
}

__global__ __launch_bounds__(NTHR)
void sphconv_kernel(const float* __restrict__ x,
                    const unsigned short* __restrict__ wt,
                    float* __restrict__ out) {
    __shared__ union SM {
        unsigned short xt[NSLOT * 8 * 64];   // [slot][b][i_chunk64] bf16, 51200 B, swizzled
        float          ot[2 * 128 * 49];     // [b&1][o][k] f32 epilogue bounce, 50176 B
    } sm;

    const int tid  = threadIdx.x;
    const int b0   = blockIdx.x * BB;
    const int wid  = tid >> 6;
    const int lane = tid & 63;
    const int l15  = lane & 15;
    const int l4   = lane >> 4;
    const int otile  = wid & 7;     // o-tile (16 o's each)
    const int parity = wid >> 3;    // M-tile parity this wave handles
    const int nt     = 13 - parity; // 13 or 12 M-tiles
    const unsigned asw = ((unsigned)(l15 & 7)) << 4;  // read-side XOR swizzle

    f32x4 acc[13];
#pragma unroll
    for (int tt = 0; tt < 13; ++tt) acc[tt] = (f32x4){0.f, 0.f, 0.f, 0.f};

    // ---- two i-chunks of 64 ----
#pragma unroll 1
    for (int c = 0; c < 2; ++c) {
        if (c) __syncthreads();   // WAR: previous chunk's reads done before restage

        // stage x -> LDS bf16, layout [slot][b][i], row = slot*8+b (128 B),
        // in-row byte offset (i*2) XOR ((row&7)<<4) = (i*2) ^ (b<<4)
        {
            int b   = tid >> 7;        // 0..7
            int rem = tid & 127;
            int iL  = rem >> 1;        // 0..63
            int seg = rem & 1;
            int kbase = seg * 23;
            int cnt   = 23 - seg;      // 23 or 22 -> 45 total
            const float* src = x + ((size_t)(b0 + b) * 128 + (size_t)(c * 64 + iL)) * NK + kbase;
            unsigned inrow = ((unsigned)(iL * 2)) ^ ((unsigned)b << 4);
#pragma unroll
            for (int j = 0; j < 23; ++j) {
                if (j < cnt) {
                    int k    = kbase + j;
                    int slot = k + kgrp(k);
                    float v  = src[j];
                    __hip_bfloat16 h = __float2bfloat16(v);
                    unsigned short u;
                    __builtin_memcpy(&u, &h, 2);
                    unsigned byte = (unsigned)(slot * 8 + b) * 128u + inrow;
                    *(unsigned short*)((char*)sm.xt + byte) = u;
                }
            }
        }
        __syncthreads();

        // ---- MFMA over this chunk's 2 K-steps ----
        bf16x8 Bf[2];
        int gcur = -1;
#pragma unroll
        for (int tt = 0; tt < 13; ++tt) {
            if (tt < nt) {
                const int t = parity + 2 * tt;
                const int g = (t >= 16) ? 4 : (t >= 9) ? 3 : (t >= 4) ? 2 : (t >= 1) ? 1 : 0;
                if (g != gcur) {   // wave-uniform branch; B from global (L2-resident)
                    gcur = g;
                    const unsigned short* wp =
                        wt + ((size_t)(g * 128 + otile * 16 + l15) << 7) + c * 64 + l4 * 8;
                    Bf[0] = *(const bf16x8*)(wp);
                    Bf[1] = *(const bf16x8*)(wp + 32);
                }
                const unsigned rowb = (unsigned)(16 * t + l15) * 128u;
#pragma unroll
                for (int ksl = 0; ksl < 2; ++ksl) {
                    bf16x8 Af = *(const bf16x8*)((const char*)sm.xt +
                                 (rowb + ((((unsigned)ksl * 64) + ((unsigned)l4 * 16)) ^ asw)));
                    acc[tt] = __builtin_amdgcn_mfma_f32_16x16x32_bf16(Af, Bf[ksl], acc[tt], 0, 0, 0);
                }
            }
        }
    }

    // ---- epilogue: 4 passes over b-pairs, LDS bounce for contiguous k-row stores ----
    // D-layout: o = otile*16 + (lane&15); row-in-tile = (lane>>4)*4 + e
    //   -> b = 4*((lane>>4)&1) + e, slot = 2t + (lane>>5)
    const int q14 = (lane >> 4) & 1;
    const int hi  = lane >> 5;
#pragma unroll
    for (int p = 0; p < 4; ++p) {
        __syncthreads();   // also protects xt reads (p=0) / previous readback
        if (q14 == (p >> 1)) {
            const int e0 = (p & 1) * 2;
#pragma unroll
            for (int tt = 0; tt < 13; ++tt) {
                if (tt < nt) {
                    const int t = parity + 2 * tt;
                    const int g = (t >= 16) ? 4 : (t >= 9) ? 3 : (t >= 4) ? 2 : (t >= 1) ? 1 : 0;
                    const int slot = 2 * t + hi;
                    const bool pad = hi && (t == 0 || t == 3 || t == 8 || t == 15 || t == 24);
                    if (!pad) {
                        const int k = slot - g;
                        const int o = otile * 16 + l15;
                        sm.ot[o * 49 + k]         = acc[tt][e0];      // b even
                        sm.ot[(128 + o) * 49 + k] = acc[tt][e0 + 1];  // b odd
                    }
                }
            }
        }
        __syncthreads();
        {
            int row = tid >> 2;          // 0..255 = (b&1)*128 + o
            int s3  = tid & 3;
            int bl  = row >> 7;
            int o   = row & 127;
            int gb  = b0 + 2 * p + bl;
            int kb  = s3 * 12;
            int cnt = (s3 == 3) ? 9 : 12;
            const float* lsrc = &sm.ot[(size_t)row * 49 + kb];
            float* gdst = out + ((size_t)gb * 128 + o) * NK + kb;
#pragma unroll
            for (int j = 0; j < 12; ++j)
                if (j < cnt) gdst[j] = lsrc[j];
        }
    }
}

extern "C" void kernel_launch(void* const* d_in, const int* in_sizes, int n_in,
                              void* d_out, int out_size, void* d_ws, size_t ws_size,
                              hipStream_t stream) {
    const float* x = (const float*)d_in[0];        // (16384, 128, 45) f32
    const float* w = (const float*)d_in[1];        // (128, 128, 5)    f32
    float* out = (float*)d_out;                    // (16384, 128, 45) f32
    unsigned short* wt = (unsigned short*)d_ws;    // 5*128*128 bf16 = 160 KB

    wprep_kernel<<<(5 * 128 * 128 + 255) / 256, 256, 0, stream>>>(w, wt);
    sphconv_kernel<<<16384 / BB, NTHR, 0, stream>>>(x, wt, out);
}